// Round 3
// baseline (364.113 us; speedup 1.0000x reference)
//
#include <hip/hip_runtime.h>
#include <cstdint>

// Fully-fused GRU: B=2048, T=256, F=64, H=32. fp32 in/out. ONE kernel.
// 512 blocks x 128 thr = 2 waves/block, wave-specialized:
//   wave 1 (producer): ring x-loads, hi/lo bf16 split, 24 x-proj MFMAs/group,
//     writes LDS (double-buffered 12KB, conflict-free [nt][col] layout),
//     one group ahead of the chain.
//   wave 0 (chain): pure recurrence with ZERO cross-lane / memory ops on the
//     dependence chain: per step 6 hh MFMAs (A=W_hh K-permuted, B=h bf16,
//     C-init = folded biases); each lane computes acts for ALL 4 C-regs
//     (dims q*4+r, +16 of batch bq — redundant across the 4 u-replica lanes,
//     which previously held identical MFMA outputs anyway) and packs its own
//     B-frag in-lane. Head fused (2 shuffles).
//   Barriers are raw s_barrier + lgkmcnt(0) only — NO vmcnt drain, so the
//   producer's HBM prefetch (1 group ahead) stays in flight across barriers.

#define TSEQ 256

typedef __attribute__((ext_vector_type(8))) short bf16x8;
typedef __attribute__((ext_vector_type(4))) float f32x4;
union BF8 { unsigned u[4]; bf16x8 v; };

__device__ __forceinline__ unsigned bfr(float f) {            // bf16 RNE in hi16
    unsigned u = __float_as_uint(f);
    return u + 0x7fffu + ((u >> 16) & 1u);
}
__device__ __forceinline__ unsigned packhi(unsigned a, unsigned b) {
    return __builtin_amdgcn_perm(b, a, 0x07060302u);          // hi16(a)|hi16(b)<<16
}
// 8 fp32 -> hi (truncated bf16) + lo (bf16 of residual): 3-term-quality products
__device__ __forceinline__ void cvt2(const float4& f0, const float4& f1,
                                     bf16x8& hi, bf16x8& lo) {
    float f[8] = {f0.x,f0.y,f0.z,f0.w, f1.x,f1.y,f1.z,f1.w};
    BF8 H, L;
    #pragma unroll
    for (int d = 0; d < 4; ++d) {
        float a = f[2*d], b = f[2*d+1];
        unsigned ua = __float_as_uint(a), ub = __float_as_uint(b);
        float ra = a - __uint_as_float(ua & 0xffff0000u);
        float rb = b - __uint_as_float(ub & 0xffff0000u);
        H.u[d] = packhi(ua, ub);
        L.u[d] = packhi(bfr(ra), bfr(rb));
    }
    hi = H.v; lo = L.v;
}
__device__ __forceinline__ float sigx(float v) {
    return __builtin_amdgcn_rcpf(1.f + exp2f(-1.4426950408889634f * v));
}
__device__ __forceinline__ float tanhx(float v) {
    float e = exp2f(-2.8853900817779268f * fabsf(v));
    return copysignf((1.f - e) * __builtin_amdgcn_rcpf(1.f + e), v);
}

#define MFMA16(A, B, C) __builtin_amdgcn_mfma_f32_16x16x32_bf16((A), (B), (C), 0, 0, 0)

// barrier WITHOUT the compiler's vmcnt(0) drain: producer's in-flight HBM
// prefetch (needed a full group later) survives the sync. LDS ops are
// drained (lgkmcnt) and fenced on both sides.
__device__ __forceinline__ void barrier_nodrain() {
    asm volatile("s_waitcnt lgkmcnt(0)" ::: "memory");
    __builtin_amdgcn_s_barrier();
    asm volatile("" ::: "memory");
}

__global__ __launch_bounds__(128, 1)
void gru_fused(const float* __restrict__ x, const float* __restrict__ W_ih,
               const float* __restrict__ W_hh, const float* __restrict__ b_ih,
               const float* __restrict__ b_hh, const float* __restrict__ W_head,
               const float* __restrict__ b_head, float* __restrict__ out)
{
    __shared__ float xsh[2][1536];                 // [buf][nt*256 + col_lane*4 + r]
    const int tid  = threadIdx.x;
    const int wid  = tid >> 6;                     // 0 = chain wave, 1 = producer
    const int lane = tid & 63;
    const int m = lane & 15, q = lane >> 4;
    const int bq = m & 3, u = m >> 2;              // batch-in-wave, step-in-group
    const int b0 = blockIdx.x * 4;

    // ===================== producer persistent state =====================
    bf16x8 Aih[6][2];
    float4 ring[4];
    const float* xcol = x + ((size_t)(b0 + bq)*TSEQ + u)*64 + q*8;
    auto ldring = [&](int grp) {
        const float* p = xcol + grp*256;           // grp*4 steps * 64 floats
        ring[0] = ((const float4*)p)[0];        ring[1] = ((const float4*)p)[1];
        ring[2] = ((const float4*)(p+32))[0];   ring[3] = ((const float4*)(p+32))[1];
    };
    auto projwrite = [&](int buf) {                // ring -> x-proj -> LDS[buf]
        bf16x8 Xh0, Xl0, Xh1, Xl1;
        cvt2(ring[0], ring[1], Xh0, Xl0);
        cvt2(ring[2], ring[3], Xh1, Xl1);
        #pragma unroll
        for (int nt = 0; nt < 6; ++nt) {
            f32x4 a = MFMA16(Aih[nt][0], Xh0, ((f32x4){0.f,0.f,0.f,0.f}));
            a = MFMA16(Aih[nt][0], Xl0, a);
            a = MFMA16(Aih[nt][1], Xh1, a);
            a = MFMA16(Aih[nt][1], Xl1, a);
            *(f32x4*)&xsh[buf][nt*256 + lane*4] = a;   // stride-4: conflict-free
        }
    };

    // ===================== chain persistent state =====================
    bf16x8 Awh[6];
    f32x4 FRZ[4], BN0, BN1, FN0, FN1;
    unsigned Hd[4] = {0u, 0u, 0u, 0u};             // h B-frag dwords (bf16 pairs)
    float hL[4] = {0.f,0.f,0.f,0.f};               // h dims q*4+r   (fp32, in-lane)
    float hH[4] = {0.f,0.f,0.f,0.f};               // h dims q*4+r+16

    if (wid == 1) {
        // ---- W_ih A-frags (plain bf16): A[m][c*32+q*8+j] = W_ih[nt*16+m][...]
        #pragma unroll
        for (int nt = 0; nt < 6; ++nt)
            #pragma unroll
            for (int c = 0; c < 2; ++c) {
                const float* wp = W_ih + (nt*16 + m)*64 + c*32 + q*8;
                BF8 t;
                #pragma unroll
                for (int d = 0; d < 4; ++d) t.u[d] = packhi(bfr(wp[2*d]), bfr(wp[2*d+1]));
                Aih[nt][c] = t.v;
            }
        ldring(0);
        projwrite(0);                              // group-0 data into buf 0
        ldring(1);
    } else {
        // ---- W_hh A-frags, K-permuted: pos p=q*8+j <-> dim (p>>1)+16*(p&1)
        #pragma unroll
        for (int nt = 0; nt < 6; ++nt) {
            const float* wp = W_hh + (nt*16 + m)*32;
            BF8 t;
            #pragma unroll
            for (int d = 0; d < 4; ++d) {
                int dd = q*4 + d;
                t.u[d] = packhi(bfr(wp[dd]), bfr(wp[dd + 16]));
            }
            Awh[nt] = t.v;
        }
        // ---- biases: C-init vectors (component reg <-> gate nt*16+q*4+reg)
        #pragma unroll
        for (int nt = 0; nt < 4; ++nt) {
            f32x4 t;
            #pragma unroll
            for (int r = 0; r < 4; ++r) { int g = nt*16 + q*4 + r; t[r] = b_ih[g] + b_hh[g]; }
            FRZ[nt] = t;
        }
        #pragma unroll
        for (int r = 0; r < 4; ++r) {
            BN0[r] = b_hh[64+q*4+r]; BN1[r] = b_hh[80+q*4+r];
            FN0[r] = b_ih[64+q*4+r]; FN1[r] = b_ih[80+q*4+r];
        }
    }
    barrier_nodrain();                             // buf0 ready

    const int s0 = (q << 4) + bq;                  // xp source column base
    for (int g = 0; g < 64; ++g) {
        if (wid == 1) {
            // producer: stage group g+1 into buf[(g+1)&1] (chain is in buf[g&1])
            if (g < 63) {
                projwrite((g + 1) & 1);
                ldring(g + 2 < 64 ? g + 2 : 63);
            }
        } else {
            // chain: read this group's x-pre vectors (24 ds_read_b128, off-chain)
            const int cbuf = g & 1;
            f32x4 xpv[4][6];
            #pragma unroll
            for (int s = 0; s < 4; ++s)
                #pragma unroll
                for (int nt = 0; nt < 6; ++nt)
                    xpv[s][nt] = *(const f32x4*)&xsh[cbuf][nt*256 + (s0 + 4*s)*4];

            #pragma unroll
            for (int s = 0; s < 4; ++s) {
                BF8 bh; bh.u[0]=Hd[0]; bh.u[1]=Hd[1]; bh.u[2]=Hd[2]; bh.u[3]=Hd[3];
                f32x4 a0 = MFMA16(Awh[0], bh.v, FRZ[0]);
                f32x4 a1 = MFMA16(Awh[1], bh.v, FRZ[1]);
                f32x4 a2 = MFMA16(Awh[2], bh.v, FRZ[2]);
                f32x4 a3 = MFMA16(Awh[3], bh.v, FRZ[3]);
                f32x4 a4 = MFMA16(Awh[4], bh.v, BN0);
                f32x4 a5 = MFMA16(Awh[5], bh.v, BN1);

                // in-lane acts for all 4 regs (dims q*4+r, +16 of batch bq);
                // identical values across the 4 u-replica lanes -> no exchange.
                #pragma unroll
                for (int r = 0; r < 4; ++r) {
                    float rL = sigx(xpv[s][0][r] + a0[r]);
                    float rH = sigx(xpv[s][1][r] + a1[r]);
                    float zL = sigx(xpv[s][2][r] + a2[r]);
                    float zH = sigx(xpv[s][3][r] + a3[r]);
                    float tL = tanhx(xpv[s][4][r] + FN0[r] + rL * a4[r]);
                    float tH = tanhx(xpv[s][5][r] + FN1[r] + rH * a5[r]);
                    float nL = tL + zL * (hL[r] - tL);
                    float nH = tH + zH * (hH[r] - tH);
                    hL[r] = nL; hH[r] = nH;
                    Hd[r] = packhi(bfr(nL), bfr(nH));
                }
            }
        }
        barrier_nodrain();
    }

    // ---- head: chain lane holds fp32 h dims (q*4+r, +16) r=0..3 of batch bq
    if (wid == 0) {
        float v = 0.f;
        #pragma unroll
        for (int r = 0; r < 4; ++r)
            v += hL[r] * W_head[q*4 + r] + hH[r] * W_head[16 + q*4 + r];
        v += __shfl_xor(v, 16, 64);                // sum over q (lane bits 4,5)
        v += __shfl_xor(v, 32, 64);
        if (lane < 4) out[b0 + lane] = sigx(v + b_head[0]);
    }
}

extern "C" void kernel_launch(void* const* d_in, const int* in_sizes, int n_in,
                              void* d_out, int out_size, void* d_ws, size_t ws_size,
                              hipStream_t stream)
{
    const float* x      = (const float*)d_in[0];
    const float* W_ih   = (const float*)d_in[1];
    const float* W_hh   = (const float*)d_in[2];
    const float* b_ih   = (const float*)d_in[3];
    const float* b_hh   = (const float*)d_in[4];
    const float* W_head = (const float*)d_in[5];
    const float* b_head = (const float*)d_in[6];
    float* out = (float*)d_out;

    gru_fused<<<512, 128, 0, stream>>>(x, W_ih, W_hh, b_ih, b_hh,
                                       W_head, b_head, out);
}

// Round 4
// 239.364 us; speedup vs baseline: 1.5212x; 1.5212x over previous
//
#include <hip/hip_runtime.h>
#include <cstdint>

// Fully-fused GRU: B=2048, T=256, F=64, H=32. fp32 in/out. ONE kernel.
// 256 blocks x 256 thr = 4 waves/block (1 block/CU, waves spread on 4 SIMDs):
//   waves 2,3 (producers, quad 0/1): ring x-loads, hi/lo bf16 split,
//     24 x-proj MFMAs/group, write LDS (double-buffered, [col][gate] layout,
//     col stride 104 floats = 16B aligned), one group ahead of the chain.
//   waves 0,1 (chains, quad 0/1): recurrence with ZERO memory/LDS-latency ops
//     on the dependence chain. MFMA columns relabeled bq=m>>2, u=m&3 so the
//     4 replica columns of a batch are CONSECUTIVE lanes: per step,
//     6 hh MFMAs (A=W_hh K-permuted, B=h bf16, C-init = folded biases),
//     acts split across replicas (lane u computes dims q*4+u, +16: 4 sig +
//     2 tanh), then the 4-dword B-frag all-gather is 4 x v_mov_dpp quad_perm
//     broadcasts (pure VALU, no lgkm wait) instead of 4 ds_bpermute.
//     xp read as 24 scalar ds_read_b32 per 4-step group (low VGPR).
//   Barriers: raw s_barrier + lgkmcnt(0) only — producers' HBM prefetch
//   (1 group ahead) stays in flight across barriers.

#define TSEQ 256
#define CSTRIDE 104                                // floats per col (16B aligned)

typedef __attribute__((ext_vector_type(8))) short bf16x8;
typedef __attribute__((ext_vector_type(4))) float f32x4;
union BF8 { unsigned u[4]; bf16x8 v; };

__device__ __forceinline__ unsigned bfr(float f) {            // bf16 RNE in hi16
    unsigned u = __float_as_uint(f);
    return u + 0x7fffu + ((u >> 16) & 1u);
}
__device__ __forceinline__ unsigned packhi(unsigned a, unsigned b) {
    return __builtin_amdgcn_perm(b, a, 0x07060302u);          // hi16(a)|hi16(b)<<16
}
// 8 fp32 -> hi (truncated bf16) + lo (bf16 of residual): 3-term-quality products
__device__ __forceinline__ void cvt2(const float4& f0, const float4& f1,
                                     bf16x8& hi, bf16x8& lo) {
    float f[8] = {f0.x,f0.y,f0.z,f0.w, f1.x,f1.y,f1.z,f1.w};
    BF8 H, L;
    #pragma unroll
    for (int d = 0; d < 4; ++d) {
        float a = f[2*d], b = f[2*d+1];
        unsigned ua = __float_as_uint(a), ub = __float_as_uint(b);
        float ra = a - __uint_as_float(ua & 0xffff0000u);
        float rb = b - __uint_as_float(ub & 0xffff0000u);
        H.u[d] = packhi(ua, ub);
        L.u[d] = packhi(bfr(ra), bfr(rb));
    }
    hi = H.v; lo = L.v;
}
__device__ __forceinline__ float sel4(f32x4 v, int u) {
    float a = (u & 1) ? v[1] : v[0];
    float b = (u & 1) ? v[3] : v[2];
    return (u & 2) ? b : a;
}
__device__ __forceinline__ float sigx(float v) {
    return __builtin_amdgcn_rcpf(1.f + exp2f(-1.4426950408889634f * v));
}
__device__ __forceinline__ float tanhx(float v) {
    float e = exp2f(-2.8853900817779268f * fabsf(v));
    return copysignf((1.f - e) * __builtin_amdgcn_rcpf(1.f + e), v);
}

#define MFMA16(A, B, C) __builtin_amdgcn_mfma_f32_16x16x32_bf16((A), (B), (C), 0, 0, 0)

// quad_perm broadcast of lane w within each aligned 4-lane quad (pure VALU).
#define QBCAST(x, w) ((unsigned)__builtin_amdgcn_update_dpp( \
        0, (int)(x), ((w) | ((w)<<2) | ((w)<<4) | ((w)<<6)), 0xf, 0xf, true))

// barrier WITHOUT the compiler's vmcnt(0) drain: producers' in-flight HBM
// prefetch (needed a full group later) survives the sync.
__device__ __forceinline__ void barrier_nodrain() {
    asm volatile("s_waitcnt lgkmcnt(0)" ::: "memory");
    __builtin_amdgcn_s_barrier();
    asm volatile("" ::: "memory");
}

__global__ __launch_bounds__(256, 1)
void gru_fused(const float* __restrict__ x, const float* __restrict__ W_ih,
               const float* __restrict__ W_hh, const float* __restrict__ b_ih,
               const float* __restrict__ b_hh, const float* __restrict__ W_head,
               const float* __restrict__ b_head, float* __restrict__ out)
{
    // [buf][quad][col*CSTRIDE + nt*16 + q*4 + r]; col = batch + 4*step
    __shared__ float xsh[2][2][16 * CSTRIDE];
    const int tid  = threadIdx.x;
    const int wid  = tid >> 6;                     // 0,1 = chain; 2,3 = producer
    const int lane = tid & 63;
    const int m = lane & 15, q = lane >> 4;
    const int b0 = blockIdx.x * 8;

    if (wid >= 2) {
        // ===================== producer (quad pq) =====================
        const int pq = wid - 2;
        const int bq = m & 3, u = m >> 2;          // col m = (batch bq, step u)
        bf16x8 Aih[6][2];
        #pragma unroll
        for (int nt = 0; nt < 6; ++nt)
            #pragma unroll
            for (int c = 0; c < 2; ++c) {
                const float* wp = W_ih + (nt*16 + m)*64 + c*32 + q*8;
                BF8 t;
                #pragma unroll
                for (int d = 0; d < 4; ++d) t.u[d] = packhi(bfr(wp[2*d]), bfr(wp[2*d+1]));
                Aih[nt][c] = t.v;
            }
        float4 ring[4];
        const float* xcol = x + ((size_t)(b0 + pq*4 + bq)*TSEQ + u)*64 + q*8;
        auto ldring = [&](int grp) {
            const float* p = xcol + grp*256;       // grp*4 steps * 64 floats
            ring[0] = ((const float4*)p)[0];        ring[1] = ((const float4*)p)[1];
            ring[2] = ((const float4*)(p+32))[0];   ring[3] = ((const float4*)(p+32))[1];
        };
        auto projwrite = [&](int buf) {            // ring -> x-proj -> LDS[buf]
            bf16x8 Xh0, Xl0, Xh1, Xl1;
            cvt2(ring[0], ring[1], Xh0, Xl0);
            cvt2(ring[2], ring[3], Xh1, Xl1);
            #pragma unroll
            for (int nt = 0; nt < 6; ++nt) {
                f32x4 a = MFMA16(Aih[nt][0], Xh0, ((f32x4){0.f,0.f,0.f,0.f}));
                a = MFMA16(Aih[nt][0], Xl0, a);
                a = MFMA16(Aih[nt][1], Xh1, a);
                a = MFMA16(Aih[nt][1], Xl1, a);
                *(f32x4*)&xsh[buf][pq][m*CSTRIDE + nt*16 + q*4] = a;   // 16B aligned
            }
        };
        ldring(0);
        projwrite(0);                              // group-0 data into buf 0
        ldring(1);
        barrier_nodrain();                         // buf0 ready
        for (int g = 0; g < 64; ++g) {
            if (g < 63) {
                projwrite((g + 1) & 1);            // chain is in buf[g&1]
                ldring(g + 2 < 64 ? g + 2 : 63);
            }
            barrier_nodrain();
        }
    } else {
        // ===================== chain (quad cq) =====================
        const int cq = wid;
        const int bq = m >> 2, u = m & 3;          // replicas = consecutive lanes
        // ---- W_hh A-frags, K-permuted: pos p=q*8+j <-> dim (p>>1)+16*(p&1)
        bf16x8 Awh[6];
        #pragma unroll
        for (int nt = 0; nt < 6; ++nt) {
            const float* wp = W_hh + (nt*16 + m)*32;
            BF8 t;
            #pragma unroll
            for (int d = 0; d < 4; ++d) {
                int dd = q*4 + d;
                t.u[d] = packhi(bfr(wp[dd]), bfr(wp[dd + 16]));
            }
            Awh[nt] = t.v;
        }
        // ---- biases: C-init vectors (component reg <-> gate nt*16+q*4+reg)
        f32x4 FRZ[4], BN0, BN1;
        #pragma unroll
        for (int nt = 0; nt < 4; ++nt) {
            f32x4 t;
            #pragma unroll
            for (int r = 0; r < 4; ++r) { int g = nt*16 + q*4 + r; t[r] = b_ih[g] + b_hh[g]; }
            FRZ[nt] = t;
        }
        #pragma unroll
        for (int r = 0; r < 4; ++r) { BN0[r] = b_hh[64+q*4+r]; BN1[r] = b_hh[80+q*4+r]; }
        const float fn0 = b_ih[64 + q*4 + u], fn1 = b_ih[80 + q*4 + u];

        unsigned Hd[4] = {0u, 0u, 0u, 0u};         // h B-frag dwords (bf16 pairs)
        float hOL = 0.f, hOH = 0.f;                // own h dims (q*4+u, +16), fp32
        barrier_nodrain();                         // buf0 ready

        for (int g = 0; g < 64; ++g) {
            const int cbuf = g & 1;
            // this group's x-pre scalars: 24 ds_read_b32, off the dep chain
            float xp[4][6];
            #pragma unroll
            for (int s = 0; s < 4; ++s) {
                const float* rp = &xsh[cbuf][cq][(bq + 4*s)*CSTRIDE + q*4 + u];
                #pragma unroll
                for (int nt = 0; nt < 6; ++nt) xp[s][nt] = rp[nt*16];
            }
            #pragma unroll
            for (int s = 0; s < 4; ++s) {
                BF8 bh; bh.u[0]=Hd[0]; bh.u[1]=Hd[1]; bh.u[2]=Hd[2]; bh.u[3]=Hd[3];
                f32x4 a0 = MFMA16(Awh[0], bh.v, FRZ[0]);
                f32x4 a1 = MFMA16(Awh[1], bh.v, FRZ[1]);
                f32x4 a2 = MFMA16(Awh[2], bh.v, FRZ[2]);
                f32x4 a3 = MFMA16(Awh[3], bh.v, FRZ[3]);
                f32x4 a4 = MFMA16(Awh[4], bh.v, BN0);
                f32x4 a5 = MFMA16(Awh[5], bh.v, BN1);

                float r0 = sigx(xp[s][0] + sel4(a0, u));
                float r1 = sigx(xp[s][1] + sel4(a1, u));
                float z0 = sigx(xp[s][2] + sel4(a2, u));
                float z1 = sigx(xp[s][3] + sel4(a3, u));
                float t0 = tanhx(xp[s][4] + fn0 + r0 * sel4(a4, u));
                float t1 = tanhx(xp[s][5] + fn1 + r1 * sel4(a5, u));
                float hNL = t0 + z0 * (hOL - t0);
                float hNH = t1 + z1 * (hOH - t1);
                hOL = hNL; hOH = hNH;

                // B-frag all-gather within the 4-lane replica quad: pure VALU.
                unsigned pk = packhi(bfr(hNL), bfr(hNH));
                Hd[0] = QBCAST(pk, 0);
                Hd[1] = QBCAST(pk, 1);
                Hd[2] = QBCAST(pk, 2);
                Hd[3] = QBCAST(pk, 3);
            }
            barrier_nodrain();
        }

        // ---- head: lane holds fp32 h dims (q*4+u, +16) of batch bq
        float v = hOL * W_head[q*4 + u] + hOH * W_head[16 + q*4 + u];
        v += __shfl_xor(v, 1, 64);                 // sum over u (lane bits 0,1)
        v += __shfl_xor(v, 2, 64);
        v += __shfl_xor(v, 16, 64);                // sum over q (lane bits 4,5)
        v += __shfl_xor(v, 32, 64);
        if (lane < 16 && (lane & 3) == 0)
            out[b0 + cq*4 + (lane >> 2)] = sigx(v + b_head[0]);
    }
}

extern "C" void kernel_launch(void* const* d_in, const int* in_sizes, int n_in,
                              void* d_out, int out_size, void* d_ws, size_t ws_size,
                              hipStream_t stream)
{
    const float* x      = (const float*)d_in[0];
    const float* W_ih   = (const float*)d_in[1];
    const float* W_hh   = (const float*)d_in[2];
    const float* b_ih   = (const float*)d_in[3];
    const float* b_hh   = (const float*)d_in[4];
    const float* W_head = (const float*)d_in[5];
    const float* b_head = (const float*)d_in[6];
    float* out = (float*)d_out;

    gru_fused<<<256, 256, 0, stream>>>(x, W_ih, W_hh, b_ih, b_hh,
                                       W_head, b_head, out);
}